// Round 3
// baseline (66.952 us; speedup 1.0000x reference)
//
#include <hip/hip_runtime.h>

// BitLayer: y[n,b] = OR_i ( x[i,b] & (u[i,n,b] < kernel[i,n]) )
// u = jax.random.uniform(jax.random.key(42), (1024,1024,256), f32), threefry2x32.
//
// Structure: pack x into transposed bitmasks xmT[b*32+w] (32 KB), then one
// block per (b, n-chunk): b block-uniform -> masks are scalar loads (all 32
// words = 128 contiguous bytes, prefetched up front); active-i walk is
// wave-uniform; kern[i*1024+n] coalesced across lanes. Walk processes 8
// active i's per batch (8 independent loads + 8 threefries in flight) with
// one __all(done) exit check per batch. Padding a batch with the first index
// is correct: duplicate trials are idempotent under OR.

#define INPUT_DIM 1024
#define NUM_OUTPUTS 1024
#define BIT_SIZE 256

__device__ __forceinline__ uint32_t rotl32(uint32_t v, int r) {
    return (v << r) | (v >> (32 - r));
}

// JAX threefry2x32: key (k0,k1), counter (x0,x1) -> 2 output words in-place.
__device__ __forceinline__ void threefry2x32(uint32_t k0, uint32_t k1,
                                             uint32_t& x0, uint32_t& x1) {
    const uint32_t ks0 = k0;
    const uint32_t ks1 = k1;
    const uint32_t ks2 = k0 ^ k1 ^ 0x1BD11BDAu;
    x0 += ks0;
    x1 += ks1;
#define TF_ROUND(r) { x0 += x1; x1 = rotl32(x1, (r)); x1 ^= x0; }
    TF_ROUND(13) TF_ROUND(15) TF_ROUND(26) TF_ROUND(6)
    x0 += ks1; x1 += ks2 + 1u;
    TF_ROUND(17) TF_ROUND(29) TF_ROUND(16) TF_ROUND(24)
    x0 += ks2; x1 += ks0 + 2u;
    TF_ROUND(13) TF_ROUND(15) TF_ROUND(26) TF_ROUND(6)
    x0 += ks0; x1 += ks1 + 3u;
    TF_ROUND(17) TF_ROUND(29) TF_ROUND(16) TF_ROUND(24)
    x0 += ks1; x1 += ks2 + 4u;
    TF_ROUND(13) TF_ROUND(15) TF_ROUND(26) TF_ROUND(6)
    x0 += ks2; x1 += ks0 + 5u;
#undef TF_ROUND
}

// Pack x (1024x256 int32 0/1) into TRANSPOSED bitmasks:
//   xmT[b*32 + w] bit j = x[(w*32+j)*256 + b]
// Grid 32 blocks (w) x 256 threads (b). Loads coalesced across lanes.
__global__ __launch_bounds__(256) void pack_x_kernel(const int* __restrict__ x,
                                                     uint32_t* __restrict__ xmT) {
    const int b = threadIdx.x;
    const int w = blockIdx.x;  // 0..31
    uint32_t m = 0;
#pragma unroll
    for (int j = 0; j < 32; ++j) {
        m |= (x[(((w << 5) + j) << 8) + b] != 0 ? 1u : 0u) << j;
    }
    xmT[(b << 5) + w] = m;
}

// Grid: 1024 blocks = 256 b x 4 n-chunks; 256 threads (consecutive n).
__global__ __launch_bounds__(256) void BitLayer_25391846654323_kernel(
        const uint32_t* __restrict__ xmT,  // (256, 32) packed x, transposed
        const float* __restrict__ kern,    // (1024, 1024) f32 probs
        float* __restrict__ out) {         // (1024, 256) f32 0/1
    const int b = blockIdx.x >> 2;                                 // 0..255
    const int n = ((blockIdx.x & 3) << 8) + threadIdx.x;           // 0..1023
    const uint32_t nb = ((uint32_t)n << 8) | (uint32_t)b;

    // All 32 mask words for this b: 128 contiguous block-uniform bytes.
    uint32_t mask[32];
#pragma unroll
    for (int w = 0; w < 32; ++w) mask[w] = xmT[(b << 5) + w];

    uint32_t done = 0;
    for (int w = 0; w < 32; ++w) {
        uint32_t m = mask[w];
        while (m) {
            // Extract up to 8 active input indices (wave-uniform, SALU).
            const int i0 = (w << 5) + __builtin_ctz(m);
            m &= m - 1;
            int ii[8];
            ii[0] = i0;
#pragma unroll
            for (int k = 1; k < 8; ++k) {
                if (m) { ii[k] = (w << 5) + __builtin_ctz(m); m &= m - 1; }
                else   { ii[k] = i0; }  // duplicate trial: idempotent under OR
            }
            // 8 independent coalesced loads, all in flight together.
            float p[8];
#pragma unroll
            for (int k = 0; k < 8; ++k) p[k] = kern[(ii[k] << 10) + n];
            // 8 threefries overlap the load latency.
#pragma unroll
            for (int k = 0; k < 8; ++k) {
                // linear index into u: jdx = i*2^18 + n*2^8 + b.  H = 2^27.
                // jdx <  H (i<512): bits = lane0 of threefry((jdx, jdx+H))
                // jdx >= H        : bits = lane1 of threefry((jdx-H, jdx))
                uint32_t c0 = (((uint32_t)(ii[k] & 511)) << 18) | nb;
                uint32_t c1 = c0 + (1u << 27);
                threefry2x32(0u, 42u, c0, c1);
                const uint32_t bits = (ii[k] < 512) ? c0 : c1;
                // jax uniform f32: ((bits>>9)|0x3f800000)-1.0 == (bits>>9)*2^-23
                const float u = (float)(bits >> 9) * 0x1p-23f;
                if (u < p[k]) done = 1u;
            }
            if (__all(done != 0)) goto finished;  // whole wave satisfied
        }
    }
finished:
    out[((uint32_t)n << 8) + (uint32_t)b] = done ? 1.0f : 0.0f;
}

extern "C" void kernel_launch(void* const* d_in, const int* in_sizes, int n_in,
                              void* d_out, int out_size, void* d_ws, size_t ws_size,
                              hipStream_t stream) {
    const int* x = (const int*)d_in[0];          // (1024, 256) int32
    const float* kern = (const float*)d_in[1];   // (1024, 1024) f32
    float* out = (float*)d_out;                  // (1024, 256) f32
    uint32_t* xmT = (uint32_t*)d_ws;             // 32 KB packed x bitmasks

    pack_x_kernel<<<32, 256, 0, stream>>>(x, xmT);
    BitLayer_25391846654323_kernel<<<NUM_OUTPUTS, 256, 0, stream>>>(xmT, kern, out);
}

// Round 4
// 66.476 us; speedup vs baseline: 1.0072x; 1.0072x over previous
//
#include <hip/hip_runtime.h>

// BitLayer: y[n,b] = OR_i ( x[i,b] & (u[i,n,b] < kernel[i,n]) )
// u = jax.random.uniform(jax.random.key(42), (1024,1024,256), f32), threefry2x32.
//
// Single fused kernel (no pack pass, no d_ws): one block per (b, n-chunk).
// Each block rebuilds the 32 x-mask words for its b via 4 loads/thread +
// __ballot into LDS (one barrier). Then the round-2 walk: b block-uniform,
// active-i walk wave-uniform, kern[i*1024+n] coalesced across lanes,
// per-trial __all(done) early exit.

#define INPUT_DIM 1024
#define NUM_OUTPUTS 1024
#define BIT_SIZE 256

__device__ __forceinline__ uint32_t rotl32(uint32_t v, int r) {
    return (v << r) | (v >> (32 - r));
}

// JAX threefry2x32: key (k0,k1), counter (x0,x1) -> 2 output words in-place.
__device__ __forceinline__ void threefry2x32(uint32_t k0, uint32_t k1,
                                             uint32_t& x0, uint32_t& x1) {
    const uint32_t ks0 = k0;
    const uint32_t ks1 = k1;
    const uint32_t ks2 = k0 ^ k1 ^ 0x1BD11BDAu;
    x0 += ks0;
    x1 += ks1;
#define TF_ROUND(r) { x0 += x1; x1 = rotl32(x1, (r)); x1 ^= x0; }
    TF_ROUND(13) TF_ROUND(15) TF_ROUND(26) TF_ROUND(6)
    x0 += ks1; x1 += ks2 + 1u;
    TF_ROUND(17) TF_ROUND(29) TF_ROUND(16) TF_ROUND(24)
    x0 += ks2; x1 += ks0 + 2u;
    TF_ROUND(13) TF_ROUND(15) TF_ROUND(26) TF_ROUND(6)
    x0 += ks0; x1 += ks1 + 3u;
    TF_ROUND(17) TF_ROUND(29) TF_ROUND(16) TF_ROUND(24)
    x0 += ks1; x1 += ks2 + 4u;
    TF_ROUND(13) TF_ROUND(15) TF_ROUND(26) TF_ROUND(6)
    x0 += ks2; x1 += ks0 + 5u;
#undef TF_ROUND
}

// Grid: 1024 blocks = 256 b x 4 n-chunks; 256 threads (consecutive n).
__global__ __launch_bounds__(256) void BitLayer_25391846654323_kernel(
        const int* __restrict__ x,         // (1024, 256) int32 0/1
        const float* __restrict__ kern,    // (1024, 1024) f32 probs
        float* __restrict__ out) {         // (1024, 256) f32 0/1
    const int tid = threadIdx.x;
    const int b = blockIdx.x >> 2;                         // 0..255
    const int n = ((blockIdx.x & 3) << 8) + tid;           // 0..1023
    const uint32_t nb = ((uint32_t)n << 8) | (uint32_t)b;
    const int wave = tid >> 6;
    const int lane = tid & 63;

    // Build the 32 x-mask words for this b cooperatively.
    // Chunk k: i = k*256 + tid; wave's ballot covers i in [k*256+wave*64, +64),
    // i.e. mask words (k*8 + wave*2) and (+1). Bit (i&31) == ballot bit (lane&31).
    __shared__ uint32_t smask[32];
#pragma unroll
    for (int k = 0; k < 4; ++k) {
        const int i = (k << 8) + tid;
        const unsigned long long bal = __ballot(x[(i << 8) + b] != 0);
        if ((lane & 31) == 0) {
            smask[(k << 3) + (wave << 1) + (lane >> 5)] =
                (uint32_t)(bal >> (lane & 32));
        }
    }
    __syncthreads();

    uint32_t done = 0;
    for (int w = 0; w < 32; ++w) {
        uint32_t m = smask[w];  // wave-uniform LDS broadcast
        while (m) {
            const int j = __builtin_ctz(m);
            m &= m - 1;
            const int i = (w << 5) + j;             // wave-uniform active input
            const float p = kern[(i << 10) + n];    // coalesced across lanes
            if (!done) {
                // linear index into u: jdx = i*2^18 + n*2^8 + b.  H = 2^27.
                // jdx <  H (i<512): bits = lane0 of threefry((jdx, jdx+H))
                // jdx >= H        : bits = lane1 of threefry((jdx-H, jdx))
                uint32_t c0 = (((uint32_t)(i & 511)) << 18) | nb;
                uint32_t c1 = c0 + (1u << 27);
                threefry2x32(0u, 42u, c0, c1);
                const uint32_t bits = (i < 512) ? c0 : c1;
                // jax uniform f32: ((bits>>9)|0x3f800000)-1.0 == (bits>>9)*2^-23
                const float u = (float)(bits >> 9) * 0x1p-23f;
                if (u < p) done = 1u;
            }
            if (__all(done != 0)) goto finished;  // whole wave satisfied
        }
    }
finished:
    out[((uint32_t)n << 8) + (uint32_t)b] = done ? 1.0f : 0.0f;
}

extern "C" void kernel_launch(void* const* d_in, const int* in_sizes, int n_in,
                              void* d_out, int out_size, void* d_ws, size_t ws_size,
                              hipStream_t stream) {
    const int* x = (const int*)d_in[0];          // (1024, 256) int32
    const float* kern = (const float*)d_in[1];   // (1024, 1024) f32
    float* out = (float*)d_out;                  // (1024, 256) f32

    BitLayer_25391846654323_kernel<<<NUM_OUTPUTS, 256, 0, stream>>>(x, kern, out);
}

// Round 5
// 62.791 us; speedup vs baseline: 1.0663x; 1.0587x over previous
//
#include <hip/hip_runtime.h>

// BitLayer: y[n,b] = OR_i ( x[i,b] & (u[i,n,b] < kernel[i,n]) )
// u = jax.random.uniform(jax.random.key(42), (1024,1024,256), f32), threefry2x32.
//
// Single kernel, no LDS/barrier/mask pass. One block per (b, n-chunk);
// lanes span consecutive n. Walk ALL i in static batches of 8:
//  - kern[(i<<10)+n] coalesced across lanes; x[(i<<8)+b] wave-uniform
//    broadcast (1 request) -- all 16 loads of a batch are independent and
//    their addresses are static (no mask->address dependency chain).
//  - software pipeline: batch t+1's loads issue before batch t's compute.
//  - x-bit check is wave-uniform -> free branch around the threefry.
//  - exit when __all(done); extra trials on finished lanes are idempotent.

#define INPUT_DIM 1024
#define NUM_OUTPUTS 1024
#define BIT_SIZE 256
#define BATCH 8

__device__ __forceinline__ uint32_t rotl32(uint32_t v, int r) {
    return (v << r) | (v >> (32 - r));
}

// JAX threefry2x32: key (k0,k1), counter (x0,x1) -> 2 output words in-place.
__device__ __forceinline__ void threefry2x32(uint32_t k0, uint32_t k1,
                                             uint32_t& x0, uint32_t& x1) {
    const uint32_t ks0 = k0;
    const uint32_t ks1 = k1;
    const uint32_t ks2 = k0 ^ k1 ^ 0x1BD11BDAu;
    x0 += ks0;
    x1 += ks1;
#define TF_ROUND(r) { x0 += x1; x1 = rotl32(x1, (r)); x1 ^= x0; }
    TF_ROUND(13) TF_ROUND(15) TF_ROUND(26) TF_ROUND(6)
    x0 += ks1; x1 += ks2 + 1u;
    TF_ROUND(17) TF_ROUND(29) TF_ROUND(16) TF_ROUND(24)
    x0 += ks2; x1 += ks0 + 2u;
    TF_ROUND(13) TF_ROUND(15) TF_ROUND(26) TF_ROUND(6)
    x0 += ks0; x1 += ks1 + 3u;
    TF_ROUND(17) TF_ROUND(29) TF_ROUND(16) TF_ROUND(24)
    x0 += ks1; x1 += ks2 + 4u;
    TF_ROUND(13) TF_ROUND(15) TF_ROUND(26) TF_ROUND(6)
    x0 += ks2; x1 += ks0 + 5u;
#undef TF_ROUND
}

// Grid: 1024 blocks = 256 b x 4 n-chunks; 256 threads (consecutive n).
__global__ __launch_bounds__(256) void BitLayer_25391846654323_kernel(
        const int* __restrict__ x,         // (1024, 256) int32 0/1
        const float* __restrict__ kern,    // (1024, 1024) f32 probs
        float* __restrict__ out) {         // (1024, 256) f32 0/1
    const int tid = threadIdx.x;
    const int b = blockIdx.x >> 2;                         // 0..255
    const int n = ((blockIdx.x & 3) << 8) + tid;           // 0..1023
    const uint32_t nb = ((uint32_t)n << 8) | (uint32_t)b;

    uint32_t done = 0;

    // Prefetch batch 0 -- first instructions of the kernel, no dependencies.
    int xb[BATCH];
    float p[BATCH];
#pragma unroll
    for (int k = 0; k < BATCH; ++k) {
        xb[k] = x[(k << 8) + b];           // wave-uniform broadcast
        p[k] = kern[(k << 10) + n];        // coalesced
    }

    for (int i0 = 0; i0 < INPUT_DIM; i0 += BATCH) {
        // Issue next batch's loads before computing this batch (pipeline).
        // Wrap the index on the last iteration: loads are valid, results unused.
        const int i1 = (i0 + BATCH) & (INPUT_DIM - 1);
        int xb2[BATCH];
        float p2[BATCH];
#pragma unroll
        for (int k = 0; k < BATCH; ++k) {
            xb2[k] = x[((i1 + k) << 8) + b];
            p2[k] = kern[((i1 + k) << 10) + n];
        }

#pragma unroll
        for (int k = 0; k < BATCH; ++k) {
            if (xb[k] != 0) {              // wave-uniform branch (b uniform)
                const int i = i0 + k;
                // linear index into u: jdx = i*2^18 + n*2^8 + b.  H = 2^27.
                // jdx <  H (i<512): bits = lane0 of threefry((jdx, jdx+H))
                // jdx >= H        : bits = lane1 of threefry((jdx-H, jdx))
                uint32_t c0 = (((uint32_t)(i & 511)) << 18) | nb;
                uint32_t c1 = c0 + (1u << 27);
                threefry2x32(0u, 42u, c0, c1);
                const uint32_t bits = (i < 512) ? c0 : c1;
                // jax uniform f32: ((bits>>9)|0x3f800000)-1.0 == (bits>>9)*2^-23
                const float u = (float)(bits >> 9) * 0x1p-23f;
                if (u < p[k]) done = 1u;
            }
        }
        if (__all(done != 0)) break;       // whole wave satisfied

#pragma unroll
        for (int k = 0; k < BATCH; ++k) { xb[k] = xb2[k]; p[k] = p2[k]; }
    }

    out[((uint32_t)n << 8) + (uint32_t)b] = done ? 1.0f : 0.0f;
}

extern "C" void kernel_launch(void* const* d_in, const int* in_sizes, int n_in,
                              void* d_out, int out_size, void* d_ws, size_t ws_size,
                              hipStream_t stream) {
    const int* x = (const int*)d_in[0];          // (1024, 256) int32
    const float* kern = (const float*)d_in[1];   // (1024, 1024) f32
    float* out = (float*)d_out;                  // (1024, 256) f32

    BitLayer_25391846654323_kernel<<<NUM_OUTPUTS, 256, 0, stream>>>(x, kern, out);
}